// Round 13
// baseline (333.013 us; speedup 1.0000x reference)
//
#include <hip/hip_runtime.h>
#include <stdint.h>

typedef unsigned short u16;
typedef __attribute__((ext_vector_type(4))) float f32x4;
typedef __attribute__((ext_vector_type(8))) short bf16x8;
typedef __attribute__((ext_vector_type(8))) u16 u16x8;

#define T_SEQ  2048
#define EMB    2048
#define HD     128
#define NHEAD  16
#define NE3    6144
#define SCALE  0.29730177875068026f   // 128^-0.25
#define LOG2E  1.44269504088896f

typedef __attribute__((address_space(3))) char* lds_t;
typedef const __attribute__((address_space(1))) char* gl_t;

__device__ __forceinline__ void gld16(const void* g, void* l) {
  __builtin_amdgcn_global_load_lds((gl_t)g, (lds_t)l, 16, 0, 0);
}

__device__ __forceinline__ u16 f2bf(float f) {
  union { float f; uint32_t u; } c; c.f = f;
  uint32_t r = c.u + 0x7fffu + ((c.u >> 16) & 1u);
  return (u16)(r >> 16);
}

// ---------------- fp32 -> bf16 conversion (memory-bound) ----------------
__global__ __launch_bounds__(256) void cvt_bf16(const float* __restrict__ in,
                                                u16* __restrict__ out, int n8) {
  int i = blockIdx.x * 256 + threadIdx.x;
  if (i >= n8) return;
  const float4* p = (const float4*)in + (size_t)i * 2;
  float4 a = p[0], b = p[1];
  u16x8 o;
  o[0]=f2bf(a.x); o[1]=f2bf(a.y); o[2]=f2bf(a.z); o[3]=f2bf(a.w);
  o[4]=f2bf(b.x); o[5]=f2bf(b.y); o[6]=f2bf(b.z); o[7]=f2bf(b.w);
  *((u16x8*)out + i) = o;
}

// ======== m201-style 8-phase BMx256 bf16 GEMM, B^T layout ========
// 512 thr, 8 waves (2M x 4N), BK=64, 2 K-tiles per iteration (t0 even->buf0,
// t1 odd->buf1; static buffers).  Per phase: one C-quadrant (mq,nq), 16 (or
// 8) MFMA; reads 12/4/8/0 via A-frag reuse across nq and B-frag reuse across
// mq; stage exactly 1 half-tile; {reads; stage; BAR; lgkmcnt(0); setprio(1);
// MFMA; setprio(0); BAR}.  vmcnt(4) ONLY at phase-3/7 ends (counted, never
// drains).  Ledger (loads: A-half=AHR, B-half=2): queue at ph0-gate =
// B(t0)4, A(t0)2*AHR, B(t1)4 -> vmcnt(4) completes B(t0)+A(t0); at ph4-gate
// = B(t1)4, A(t1)2*AHR, B(t0+2)4 -> completes B(t1)+A(t1).  Stage targets:
// ph0/1: A(t1)->buf1 (last read prev ph6); ph2/3: B(t0+2)->buf0 (last read
// ph1); ph4/5: A(t0+2)->buf0 (last read ph2); ph6/7: B(t1+2)->buf1 (last
// read ph5) — every overwrite >=1 barrier after final read.  Tail clamps
// write dead buffers or identical bytes.  Involution (row&7)<<4 on 128B
// rows, both ds_read addr and staged global src (PMC 0-conflict, R5-R12).
__device__ __forceinline__ bf16x8 frg(const char* m, int row, int ks, int lq) {
  return *(const bf16x8*)(m + row*128 + ((ks*64 + lq*16) ^ ((row & 7) << 4)));
}

template<int EPI, int BM>
__global__ __launch_bounds__(512, 2) void gemm8p(
    const u16* __restrict__ A, const u16* __restrict__ Bm, int K, int N,
    const float* __restrict__ cosT, const float* __restrict__ sinT,
    const float* __restrict__ bias,
    u16* __restrict__ Qh, u16* __restrict__ Kh, u16* __restrict__ Vt,
    float* __restrict__ Cout)
{
  constexpr int ASLAB = BM * 128;      // A tile bytes (16KB or 32KB)
  constexpr int MFR   = BM / 64;       // M-frags per quadrant (2 or 4)
  constexpr int AHB   = ASLAB / 2;     // A half-tile bytes
  constexpr int AHR   = AHB / 8192;    // gld rounds per A-half (1 or 2)
  __shared__ __align__(16) char lds[2 * (ASLAB + 32768)];

  const int tid = threadIdx.x;
  const int lane = tid & 63, w = tid >> 6;
  const int wm = w >> 2, wn = w & 3;
  const int l15 = lane & 15, lq = lane >> 4;

  constexpr int NBMd4 = (4096 / BM) / 4;
  const int region = blockIdx.x >> 4, s = blockIdx.x & 15;
  const int bM = (region % NBMd4) * 4 + (s >> 2);
  const int bN = (region / NBMd4) * 4 + (s & 3);

  const char* Ag = (const char*)(A + (size_t)bM * BM * K);
  const char* Bg = (const char*)(Bm + (size_t)bN * 256 * K);
  const int K2 = K * 2;
  const int nT = K >> 6;               // 32 K-tiles of 64

  char* LA0 = lds;
  char* LB0 = lds + ASLAB;
  char* LA1 = lds + ASLAB + 32768;
  char* LB1 = LA1 + ASLAB;

  #define STG_A(t, h, LA) do {                                           \
    _Pragma("unroll") for (int j_ = 0; j_ < AHR; ++j_) {                 \
      int lb_ = j_*8192 + tid*16;                                        \
      int row_ = (h)*(BM/2) + (lb_ >> 7);                                \
      gld16(Ag + (size_t)row_*K2 + (t)*128 + ((lb_&127) ^ ((row_&7)<<4)),\
            (LA) + (h)*AHB + lb_); } } while (0)
  #define STG_B(t, h, LB) do {                                           \
    _Pragma("unroll") for (int j_ = 0; j_ < 2; ++j_) {                   \
      int lb_ = j_*8192 + tid*16;                                        \
      int row_ = (h)*128 + (lb_ >> 7);                                   \
      gld16(Bg + (size_t)row_*K2 + (t)*128 + ((lb_&127) ^ ((row_&7)<<4)),\
            (LB) + (h)*16384 + lb_); } } while (0)
  #define RD_A(LA, mq_) _Pragma("unroll") for (int mi_ = 0; mi_ < MFR; ++mi_) \
    { _Pragma("unroll") for (int ks_ = 0; ks_ < 2; ++ks_)                     \
      Ar[mi_][ks_] = frg(LA, wm*(BM/2) + (mq_)*(BM/4) + mi_*16 + l15, ks_, lq); }
  #define RD_B(LB, nq_, Br) _Pragma("unroll") for (int ni_ = 0; ni_ < 2; ++ni_) \
    { _Pragma("unroll") for (int ks_ = 0; ks_ < 2; ++ks_)                       \
      Br[ni_][ks_] = frg(LB, wn*64 + (nq_)*32 + ni_*16 + l15, ks_, lq); }
  #define MM(mq_, nq_, Br) do { __builtin_amdgcn_s_setprio(1);                \
    _Pragma("unroll") for (int mi_ = 0; mi_ < MFR; ++mi_)                     \
    _Pragma("unroll") for (int ni_ = 0; ni_ < 2; ++ni_)                       \
    _Pragma("unroll") for (int ks_ = 0; ks_ < 2; ++ks_)                       \
      acc[(mq_)*MFR+mi_][(nq_)*2+ni_] = __builtin_amdgcn_mfma_f32_16x16x32_bf16( \
        Ar[mi_][ks_], Br[ni_][ks_], acc[(mq_)*MFR+mi_][(nq_)*2+ni_], 0,0,0);  \
    __builtin_amdgcn_s_setprio(0); } while (0)
  #define MIDBAR do { __builtin_amdgcn_s_barrier();                      \
    asm volatile("s_waitcnt lgkmcnt(0)" ::: "memory");                   \
    __builtin_amdgcn_sched_barrier(0); } while (0)
  #define ENDBAR do { __builtin_amdgcn_s_barrier();                      \
    __builtin_amdgcn_sched_barrier(0); } while (0)

  // prologue: B(0)->buf0, A(0)->buf0, B(1)->buf1 (queue order = steady state)
  STG_B(0, 0, LB0); STG_B(0, 1, LB0);
  STG_A(0, 0, LA0); STG_A(0, 1, LA0);
  STG_B(1, 0, LB1); STG_B(1, 1, LB1);
  asm volatile("s_waitcnt vmcnt(4)" ::: "memory");
  ENDBAR;

  f32x4 acc[2*MFR][4] = {};
  bf16x8 Ar[MFR][2], Br0[2][2], Br1[2][2];

  for (int it = 0; it < nT/2; ++it) {
    const int t0 = 2*it, t1 = t0 + 1;
    const int tc0 = (t0 + 2 < nT) ? t0 + 2 : nT - 1;
    const int tc1 = (t1 + 2 < nT) ? t1 + 2 : nT - 1;

    // ---- tile t0 (buf0) ----
    RD_A(LA0, 0); RD_B(LB0, 0, Br0);          // 12 (or 8) reads
    STG_A(t1, 0, LA1);
    if (MFR == 4) asm volatile("s_waitcnt lgkmcnt(8)" ::: "memory");
    MIDBAR;  MM(0, 0, Br0);  ENDBAR;          // ph0
    RD_B(LB0, 1, Br1);
    STG_A(t1, 1, LA1);
    MIDBAR;  MM(0, 1, Br1);  ENDBAR;          // ph1
    RD_A(LA0, 1);
    STG_B(tc0, 0, LB0);
    MIDBAR;  MM(1, 0, Br0);  ENDBAR;          // ph2
    STG_B(tc0, 1, LB0);
    __builtin_amdgcn_s_barrier();
    __builtin_amdgcn_sched_barrier(0);
    MM(1, 1, Br1);                            // ph3
    asm volatile("s_waitcnt vmcnt(4)" ::: "memory");
    ENDBAR;

    // ---- tile t1 (buf1) ----
    RD_A(LA1, 0); RD_B(LB1, 0, Br0);
    STG_A(tc0, 0, LA0);
    if (MFR == 4) asm volatile("s_waitcnt lgkmcnt(8)" ::: "memory");
    MIDBAR;  MM(0, 0, Br0);  ENDBAR;          // ph4
    RD_B(LB1, 1, Br1);
    STG_A(tc0, 1, LA0);
    MIDBAR;  MM(0, 1, Br1);  ENDBAR;          // ph5
    RD_A(LA1, 1);
    STG_B(tc1, 0, LB1);
    MIDBAR;  MM(1, 0, Br0);  ENDBAR;          // ph6
    STG_B(tc1, 1, LB1);
    __builtin_amdgcn_s_barrier();
    __builtin_amdgcn_sched_barrier(0);
    MM(1, 1, Br1);                            // ph7
    asm volatile("s_waitcnt vmcnt(4)" ::: "memory");
    ENDBAR;
  }
  asm volatile("s_waitcnt vmcnt(0) lgkmcnt(0)" ::: "memory");
  __builtin_amdgcn_sched_barrier(0);
  #undef STG_A
  #undef STG_B
  #undef RD_A
  #undef RD_B
  #undef MM
  #undef MIDBAR
  #undef ENDBAR

  if (EPI == 0) {
    #pragma unroll
    for (int mi = 0; mi < 2*MFR; mi++) {
      int row = bM*BM + wm*(BM/2) + mi*16 + lq*4;
      #pragma unroll
      for (int ni = 0; ni < 4; ni++) {
        int col = bN*256 + wn*64 + ni*16 + l15;
        #pragma unroll
        for (int rr = 0; rr < 4; rr++)
          Cout[(size_t)(row + rr) * N + col] = acc[mi][ni][rr];
      }
    }
  } else {
    // block-uniform segment (0=K,1=V,2=Q) and head (cbase%128 in {0,64})
    const int cbase = bN*256 + wn*64;
    const int seg  = cbase >> 11;
    const int head = (cbase >> 7) & 15;
    #pragma unroll
    for (int mi = 0; mi < 2*MFR; mi++) {
      #pragma unroll
      for (int ni = 0; ni < 4; ni++) {
        int col = cbase + ni*16 + l15;
        int d = col & 127;
        float bi = bias[col];
        f32x4 v = acc[mi][ni];
        #pragma unroll
        for (int rr = 0; rr < 4; rr++) {
          int n = bM*BM + wm*(BM/2) + mi*16 + lq*4 + rr;   // flat token = t*B+b
          float val = v[rr] + bi;
          int t = n >> 1, b = n & 1;
          int bh = b*NHEAD + head;
          if (seg == 1) {
            Vt[((size_t)bh*HD + d)*T_SEQ + t] = f2bf(val);
          } else {
            // RoPE: reference's flat reshape makes angle row = n % T
            float par = __shfl_xor(val, 1);
            int fidx = d >> 1;
            float cs = cosT[(n & (T_SEQ-1))*64 + fidx];
            float sn = sinT[(n & (T_SEQ-1))*64 + fidx];
            val = (d & 1) ? (par*sn + val*cs) : (val*cs - par*sn);
            val *= SCALE;
            u16* dst = (seg == 0) ? Kh : Qh;
            dst[((size_t)bh*T_SEQ + t)*HD + d] = f2bf(val);
          }
        }
      }
    }
  }
}

// ---------------- causal flash attention, bf16 MFMA (R12, unchanged) ------
#define PSW(row) ((((row) & 7) << 4) ^ (((row) & 8) << 2))

__global__ __launch_bounds__(512, 4) void attn_fwd(
    const u16* __restrict__ Qh, const u16* __restrict__ Kh,
    const u16* __restrict__ Vt, u16* __restrict__ O)
{
  const int i = blockIdx.x;
  const int kk = i >> 8, c = i & 255;
  const int b5 = c & 15;
  const int qb = kk ? (15 - b5) : b5;
  const int bh = (c >> 4) + kk * 16;

  const int tid = threadIdx.x, lane = tid & 63, w = tid >> 6;
  const int l15 = lane & 15, lq = lane >> 4;

  __shared__ u16 Ks[2][64*128];
  __shared__ u16 Vs[2][128*64];
  __shared__ char Ps[8][2048];

  const int q0 = qb*128 + w*16;
  bf16x8 qf[4];
  #pragma unroll
  for (int dc = 0; dc < 4; dc++)
    qf[dc] = *(const bf16x8*)(Qh + ((size_t)bh*T_SEQ + q0 + l15)*HD + dc*32 + lq*8);

  const int nkb = 2*qb + 2;

  #define STAGE_KV(t, b) do {                                              \
    _Pragma("unroll")                                                      \
    for (int j_ = 0; j_ < 2; j_++) {                                       \
      int lb_ = tid*16 + j_*8192;                                          \
      int row_ = lb_ >> 8, bir_ = lb_ & 255;                               \
      int sb_ = bir_ ^ ((row_ & 7) << 4);                                  \
      gld16((const char*)Kh + (((size_t)bh*T_SEQ + (t)*64 + row_) << 8) + sb_, \
            (char*)Ks[b] + lb_);                                           \
    }                                                                      \
    _Pragma("unroll")                                                      \
    for (int j_ = 0; j_ < 2; j_++) {                                       \
      int lb_ = tid*16 + j_*8192;                                          \
      int row_ = lb_ >> 7, bir_ = lb_ & 127;                               \
      int sb_ = bir_ ^ ((row_ & 7) << 4);                                  \
      gld16((const char*)Vt + ((size_t)(bh*HD + row_)*T_SEQ)*2 + (t)*128 + sb_, \
            (char*)Vs[b] + lb_);                                           \
    }                                                                      \
  } while (0)

  STAGE_KV(0, 0);
  STAGE_KV(1, 1);

  f32x4 o[8] = {};
  float m[4], l_[4];
  #pragma unroll
  for (int r = 0; r < 4; r++) { m[r] = -1e30f; l_[r] = 0.f; }

  for (int kb = 0; kb < nkb; ++kb) {
    asm volatile("s_waitcnt vmcnt(4)" ::: "memory");
    __builtin_amdgcn_s_barrier();
    __builtin_amdgcn_sched_barrier(0);

    const char* Kb = (const char*)Ks[kb & 1];
    const char* Vb = (const char*)Vs[kb & 1];

    f32x4 sacc[4];
    #pragma unroll
    for (int nf = 0; nf < 4; nf++) {
      f32x4 z = {};
      sacc[nf] = z;
      #pragma unroll
      for (int dc = 0; dc < 4; dc++) {
        int row = nf*16 + l15;
        int bir = (dc*64 + lq*16) ^ ((row & 7) << 4);
        bf16x8 kf = *(const bf16x8*)(Kb + row*256 + bir);
        sacc[nf] = __builtin_amdgcn_mfma_f32_16x16x32_bf16(qf[dc], kf, sacc[nf], 0, 0, 0);
      }
    }

    if (kb*64 + 63 > q0) {
      #pragma unroll
      for (int nf = 0; nf < 4; nf++)
        #pragma unroll
        for (int r = 0; r < 4; r++) {
          int key = kb*64 + nf*16 + l15;
          int qr  = q0 + lq*4 + r;
          if (key > qr) sacc[nf][r] = -1e30f;
        }
    }

    #pragma unroll
    for (int r = 0; r < 4; r++) {
      float mx = fmaxf(fmaxf(sacc[0][r], sacc[1][r]), fmaxf(sacc[2][r], sacc[3][r]));
      mx = fmaxf(mx, __shfl_xor(mx, 1));
      mx = fmaxf(mx, __shfl_xor(mx, 2));
      mx = fmaxf(mx, __shfl_xor(mx, 4));
      mx = fmaxf(mx, __shfl_xor(mx, 8));
      float newm = fmaxf(m[r], mx);
      float scale = exp2f((m[r] - newm) * LOG2E);
      float sum = 0.f;
      #pragma unroll
      for (int nf = 0; nf < 4; nf++) {
        float p = exp2f((sacc[nf][r] - newm) * LOG2E);
        sacc[nf][r] = p;
        sum += p;
      }
      sum += __shfl_xor(sum, 1);
      sum += __shfl_xor(sum, 2);
      sum += __shfl_xor(sum, 4);
      sum += __shfl_xor(sum, 8);
      l_[r] = l_[r] * scale + sum;
      m[r] = newm;
      #pragma unroll
      for (int nf = 0; nf < 8; nf++) o[nf][r] *= scale;
    }

    #pragma unroll
    for (int nf = 0; nf < 4; nf++)
      #pragma unroll
      for (int r = 0; r < 4; r++) {
        int prow = lq*4 + r;
        int pbyte = prow*128 + (((nf*16 + l15)*2) ^ PSW(prow));
        *(u16*)(Ps[w] + pbyte) = f2bf(sacc[nf][r]);
      }

    #pragma unroll
    for (int kc = 0; kc < 2; kc++) {
      int pb = (kc*64 + lq*16) ^ PSW(l15);
      bf16x8 pf = *(const bf16x8*)(Ps[w] + l15*128 + pb);
      #pragma unroll
      for (int nf = 0; nf < 8; nf++) {
        int row = nf*16 + l15;
        int bir = (kc*64 + lq*16) ^ ((row & 7) << 4);
        bf16x8 vf = *(const bf16x8*)(Vb + row*128 + bir);
        o[nf] = __builtin_amdgcn_mfma_f32_16x16x32_bf16(pf, vf, o[nf], 0, 0, 0);
      }
    }

    __builtin_amdgcn_s_barrier();
    const int tnext = (kb + 2 < nkb) ? kb + 2 : nkb - 1;
    STAGE_KV(tnext, kb & 1);
  }
  asm volatile("s_waitcnt vmcnt(0)" ::: "memory");
  #undef STAGE_KV

  const int b = bh >> 4, h = bh & 15;
  #pragma unroll
  for (int r = 0; r < 4; r++) {
    float inv = 1.0f / l_[r];
    int t = q0 + lq*4 + r;
    size_t base = ((size_t)(t*2 + b))*EMB + h*HD;
    #pragma unroll
    for (int nf = 0; nf < 8; nf++)
      O[base + nf*16 + l15] = f2bf(o[nf][r] * inv);
  }
}

// ---------------- launch ----------------
extern "C" void kernel_launch(void* const* d_in, const int* in_sizes, int n_in,
                              void* d_out, int out_size, void* d_ws, size_t ws_size,
                              hipStream_t stream) {
  const float* query = (const float*)d_in[0];
  const float* Wqkv  = (const float*)d_in[1];
  const float* bqkv  = (const float*)d_in[2];
  const float* Wo    = (const float*)d_in[3];
  // d_in[4] = bo — reference does NOT add it
  const float* fcos  = (const float*)d_in[5];
  const float* fsin  = (const float*)d_in[6];
  float* out = (float*)d_out;
  char* ws = (char*)d_ws;

  // workspace layout (bytes), total 96MB
  u16* WQb = (u16*)(ws + 0);          // 6144x2048 bf16 = 25165824
  u16* WOb = (u16*)(ws + 25165824);   // 2048x2048 bf16 =  8388608
  u16* A1  = (u16*)(ws + 33554432);   // 4096x2048 bf16 (query; reused as attn out)
  u16* QH  = (u16*)(ws + 50331648);   // [32][2048][128] bf16
  u16* KH  = (u16*)(ws + 67108864);
  u16* VT  = (u16*)(ws + 83886080);   // [32][128][2048] bf16  (end: 100663296)

  cvt_bf16<<<4096, 256, 0, stream>>>(query, A1, 1048576);
  cvt_bf16<<<6144, 256, 0, stream>>>(Wqkv, WQb, 1572864);
  cvt_bf16<<<2048, 256, 0, stream>>>(Wo,   WOb,  524288);

  gemm8p<1, 256><<<384, 512, 0, stream>>>(A1, WQb, 2048, NE3,
                                          fcos, fsin, bqkv, QH, KH, VT, nullptr);

  attn_fwd<<<512, 512, 0, stream>>>(QH, KH, VT, A1);

  gemm8p<0, 128><<<256, 512, 0, stream>>>(A1, WOb, 2048, EMB,
                                          nullptr, nullptr, nullptr,
                                          nullptr, nullptr, nullptr, out);
}